// Round 3
// baseline (2697.251 us; speedup 1.0000x reference)
//
#include <hip/hip_runtime.h>

// ---------------- problem constants ----------------
#define DIM    384
#define HEADS  12
#define NPIX   3136      // 56*56
#define BATCH  32
#define AGENTS 49
#define HD     32

typedef unsigned short u16;
typedef unsigned int   u32;
typedef __attribute__((ext_vector_type(8))) short short8;   // 8 bf16 (4 VGPRs)
typedef __attribute__((ext_vector_type(4))) float f32x4;

__device__ __forceinline__ float bf2f(u16 u) { return __uint_as_float(((u32)u) << 16); }
__device__ __forceinline__ u16 f2bf(float f) {
    u32 i = __float_as_uint(f);
    u32 r = i + 0x7fffu + ((i >> 16) & 1u);   // round-to-nearest-even
    return (u16)(r >> 16);
}

// unpack 32 contiguous bf16 -> 32 floats (16B-aligned source)
__device__ __forceinline__ void unpack_row32(const u16* p, float* f) {
    const uint4* q = (const uint4*)p;
#pragma unroll
    for (int i = 0; i < 4; i++) {
        uint4 u = q[i];
        u32 w0 = u.x, w1 = u.y, w2 = u.z, w3 = u.w;
        f[i*8+0] = __uint_as_float(w0 << 16); f[i*8+1] = __uint_as_float(w0 & 0xffff0000u);
        f[i*8+2] = __uint_as_float(w1 << 16); f[i*8+3] = __uint_as_float(w1 & 0xffff0000u);
        f[i*8+4] = __uint_as_float(w2 << 16); f[i*8+5] = __uint_as_float(w2 & 0xffff0000u);
        f[i*8+6] = __uint_as_float(w3 << 16); f[i*8+7] = __uint_as_float(w3 & 0xffff0000u);
    }
}

// generic: src fp32 [R][C] -> dst bf16 [C][R]  (R, C multiples of 64)
__global__ __launch_bounds__(256) void transpose_mat(const float* __restrict__ src, u16* __restrict__ dst,
                                                     int R, int C) {
    __shared__ u16 tile[64][65];
    int c0 = blockIdx.x * 64, r0 = blockIdx.y * 64;
    int t0 = threadIdx.x & 63, t1 = threadIdx.x >> 6;
#pragma unroll
    for (int i = 0; i < 16; i++) {
        int r = t1 + i*4;
        tile[t0][r] = f2bf(src[(size_t)(r0 + r)*C + c0 + t0]);
    }
    __syncthreads();
#pragma unroll
    for (int i = 0; i < 16; i++) {
        int c = t1 + i*4;
        dst[(size_t)(c0 + c)*R + r0 + t0] = tile[c][t0];
    }
}

// ---------------- bilinear bias upsample 7x7 -> 56x56 (fp32 -> fp32) ----------------
// matches jax.image.resize 'bilinear': src coord = (i+0.5)/8 - 0.5; edge renormalize == clamp for 2-tap
__global__ __launch_bounds__(256) void upsample_bias(const float* __restrict__ src, float* __restrict__ dst) {
    int idx = blockIdx.x * 256 + threadIdx.x;          // < 12*49*3136
    int xo = idx % 56; int t = idx / 56;
    int yo = t % 56;   int ha = t / 56;                // h*49 + a
    float fy = yo * 0.125f - 0.4375f;
    float fx = xo * 0.125f - 0.4375f;
    float y0f = floorf(fy), x0f = floorf(fx);
    float wy = fy - y0f, wx = fx - x0f;
    int y0 = (int)y0f, x0 = (int)x0f;
    int y0c = max(y0, 0), y1c = min(y0 + 1, 6);
    int x0c = max(x0, 0), x1c = min(x0 + 1, 6);
    const float* sp = src + (size_t)ha * 49;
    float v00 = sp[y0c*7 + x0c], v01 = sp[y0c*7 + x1c];
    float v10 = sp[y1c*7 + x0c], v11 = sp[y1c*7 + x1c];
    dst[idx] = (1.f-wy)*((1.f-wx)*v00 + wx*v01) + wy*((1.f-wx)*v10 + wx*v11);
}

// ---------------- shared MFMA fragment compute (tiles staged in As/Bs, XOR swizzle) ----------------
__device__ __forceinline__ void mfma_tile(const short* As, const short* Bs, f32x4 acc[4][4],
                                          int wm, int wn, int quad, int lr) {
#pragma unroll
    for (int ks = 0; ks < 2; ks++) {
        int g = ks*4 + quad;
        short8 af[4], bg[4];
#pragma unroll
        for (int im = 0; im < 4; im++) {
            int r = wm*64 + im*16 + lr;
            af[im] = *(const short8*)&As[r*64 + ((g ^ (r & 7)) << 3)];
        }
#pragma unroll
        for (int in_ = 0; in_ < 4; in_++) {
            int r = wn*64 + in_*16 + lr;
            bg[in_] = *(const short8*)&Bs[r*64 + ((g ^ (r & 7)) << 3)];
        }
#pragma unroll
        for (int im = 0; im < 4; im++)
#pragma unroll
            for (int in_ = 0; in_ < 4; in_++)
                acc[im][in_] = __builtin_amdgcn_mfma_f32_16x16x32_bf16(af[im], bg[in_], acc[im][in_], 0, 0, 0);
    }
}

// QKV GEMM, reading x (fp32, [b][384][3136]) with in-staging transpose + bf16 convert.
__global__ __launch_bounds__(256) void gemm_qkv(const float* __restrict__ x, const u16* __restrict__ Bw,
                                                const float* __restrict__ bias,
                                                u16* __restrict__ qb, u16* __restrict__ kb, u16* __restrict__ vb) {
    __shared__ __align__(16) short As[128*64];
    __shared__ __align__(16) short Bs[128*64];
    f32x4 acc[4][4] = {};
    const int n0 = blockIdx.x * 128;
    const int p0 = blockIdx.y * 128;
    const int bb = blockIdx.z;
    const int tid  = threadIdx.x;
    const int lane = tid & 63, wave = tid >> 6;
    const int wm = wave >> 1, wn = wave & 1;
    const int quad = lane >> 4, lr = lane & 15;
    const int ch_ = tid >> 2;            // 0..63  (channel within K-tile)
    const int seg = tid & 3;             // 0..3   (32-pixel segment)
    const int pbase = seg * 32;
    const bool segok = (p0 + pbase) < NPIX;   // NPIX % 32 == 0: segment fully valid or fully OOB

    for (int kt = 0; kt < DIM; kt += 64) {
        __syncthreads();
        // --- stage A: load 32 fp32 pixels of one channel, convert, transpose into LDS ---
        u16 vals[32];
        if (segok) {
            const float4* xp = (const float4*)(x + ((size_t)bb*DIM + kt + ch_)*NPIX + p0 + pbase);
#pragma unroll
            for (int j = 0; j < 8; j++) {
                float4 u = xp[j];
                vals[j*4+0] = f2bf(u.x); vals[j*4+1] = f2bf(u.y);
                vals[j*4+2] = f2bf(u.z); vals[j*4+3] = f2bf(u.w);
            }
        } else {
#pragma unroll
            for (int i = 0; i < 32; i++) vals[i] = 0;
        }
#pragma unroll
        for (int i = 0; i < 32; i++) {
            int r = pbase + i;           // pbase % 8 == 0 -> (r&7) == (i&7)
            As[r*64 + (((ch_ >> 3) ^ (i & 7)) << 3) + (ch_ & 7)] = (short)vals[i];
        }
        // --- stage B: qkvwT rows (k-contiguous bf16) ---
#pragma unroll
        for (int c2 = 0; c2 < 4; c2++) {
            int idx = c2*256 + tid;
            int r = idx >> 3, g = idx & 7;
            int so = r*64 + ((g ^ (r & 7)) << 3);
            *(uint4*)&Bs[so] = *(const uint4*)&Bw[(size_t)(n0 + r)*DIM + kt + g*8];
        }
        __syncthreads();
        mfma_tile(As, Bs, acc, wm, wn, quad, lr);
    }
    // --- epilogue: scatter into per-head q/k/v (bf16) ---
#pragma unroll
    for (int in_ = 0; in_ < 4; in_++) {
        int col = n0 + wn*64 + in_*16 + lr;           // < 1152
        int which = col / 384;
        int ch = col - which*384;
        int head = ch >> 5, d = ch & 31;
        float bcol = bias[col];
        u16* dstp = (which == 0) ? qb : ((which == 1) ? kb : vb);
#pragma unroll
        for (int im = 0; im < 4; im++) {
            int prow = p0 + wm*64 + im*16 + quad*4;
#pragma unroll
            for (int r = 0; r < 4; r++) {
                int pix = prow + r;
                if (pix < NPIX) {
                    float v = acc[im][in_][r] + bcol;
                    dstp[((size_t)(bb*HEADS + head)*NPIX + pix)*HD + d] = f2bf(v);
                }
            }
        }
    }
}

// proj GEMM: obuf(bf16)[100352][384] @ projwT(bf16)[384][384]^T + bias -> out = x * sigmoid(.) fp32 NCHW
__global__ __launch_bounds__(256) void gemm_proj(const u16* __restrict__ A, const u16* __restrict__ Bw,
                                                 const float* __restrict__ bias, const float* __restrict__ xin,
                                                 float* __restrict__ outp) {
    __shared__ __align__(16) short As[128*64];
    __shared__ __align__(16) short Bs[128*64];
    f32x4 acc[4][4] = {};
    const int n0 = blockIdx.x * 128, m0 = blockIdx.y * 128;
    const int tid  = threadIdx.x;
    const int lane = tid & 63, wave = tid >> 6;
    const int wm = wave >> 1, wn = wave & 1;
    const int quad = lane >> 4, lr = lane & 15;
    for (int kt = 0; kt < DIM; kt += 64) {
        __syncthreads();
#pragma unroll
        for (int c = 0; c < 4; c++) {
            int idx = c*256 + tid;
            int r = idx >> 3, g = idx & 7;
            int so = r*64 + ((g ^ (r & 7)) << 3);
            *(uint4*)&As[so] = *(const uint4*)&A[(size_t)(m0 + r)*DIM + kt + g*8];
            *(uint4*)&Bs[so] = *(const uint4*)&Bw[(size_t)(n0 + r)*DIM + kt + g*8];
        }
        __syncthreads();
        mfma_tile(As, Bs, acc, wm, wn, quad, lr);
    }
#pragma unroll
    for (int in_ = 0; in_ < 4; in_++) {
        int col = n0 + wn*64 + in_*16 + lr;           // < 384
        float bcol = bias[col];
#pragma unroll
        for (int im = 0; im < 4; im++) {
            int rowb = m0 + wm*64 + im*16 + quad*4;
#pragma unroll
            for (int r = 0; r < 4; r++) {
                int grow = rowb + r;
                int bb = grow / NPIX;
                int pix = grow - bb*NPIX;
                float o = acc[im][in_][r] + bcol;
                float sg = 1.f / (1.f + __expf(-o));
                size_t xi = ((size_t)bb*DIM + col)*NPIX + pix;
                outp[xi] = xin[xi] * sg;
            }
        }
    }
}

// ---------------- agent pooling: 8x8 mean of q(bf16) -> agent [b][H][49][32] fp32 ----------------
__global__ __launch_bounds__(256) void pool_q(const u16* __restrict__ qb, float* __restrict__ agent) {
    int gt = blockIdx.x * 256 + threadIdx.x;          // < 32*12*49*32
    int d = gt & 31;
    int t2 = gt >> 5;
    int a = t2 % 49;
    int bh = t2 / 49;
    int ay = a / 7, ax = a % 7;
    const u16* qp = qb + (size_t)bh*NPIX*HD + d;
    float s = 0.f;
#pragma unroll
    for (int dy = 0; dy < 8; dy++)
#pragma unroll
        for (int dx = 0; dx < 8; dx++)
            s += bf2f(qp[(size_t)((ay*8 + dy)*56 + ax*8 + dx)*HD]);
    agent[gt] = s * (1.f/64.f);
}

// ---------------- stage 1: agent_v[b,h,a,:] = softmax_pix(scale*ah.k + pb1) @ V ----------------
// scores tiny (|s| <~ 1): exp without max-subtraction is exact softmax. 13 passes x 4 agents.
__global__ __launch_bounds__(512) void stage1(const u16* __restrict__ kb, const u16* __restrict__ vb,
                                              const float* __restrict__ agent, const float* __restrict__ pb1,
                                              float* __restrict__ agentv) {
    __shared__ __align__(16) float p_s[NPIX*4];       // [pix][4]
    __shared__ float ah_s[4*32];
    __shared__ float red[16*4*32];      // [g][a][d]
    __shared__ float lred[8*4];
    __shared__ float l_s[4];
    const int bh = blockIdx.x;          // b*12 + h
    const int hh = bh % HEADS;
    const int tid = threadIdx.x;
    const u16* kptr = kb + (size_t)bh*NPIX*HD;
    const u16* vptr = vb + (size_t)bh*NPIX*HD;
    const float* ahp = agent + (size_t)bh*AGENTS*HD;
    const float* pbp = pb1 + (size_t)hh*AGENTS*NPIX;
    const float scale = 0.1767766952966369f;  // 32^-0.5

    for (int pass = 0; pass < 13; pass++) {
        int a0 = pass * 4;
        int cnt = min(4, AGENTS - a0);
        if (tid < 128) {
            int a = tid >> 5, d = tid & 31;
            ah_s[tid] = (a < cnt) ? ahp[(a0 + a)*HD + d] : 0.f;
        }
        __syncthreads();
        // phase A: scores + exp for 4 agents
        float lp[4] = {0.f, 0.f, 0.f, 0.f};
        for (int pix = tid; pix < NPIX; pix += 512) {
            float kf[32];
            unpack_row32(kptr + (size_t)pix*HD, kf);
            f32x4 pv;
#pragma unroll
            for (int a = 0; a < 4; a++) {
                float s = 0.f;
#pragma unroll
                for (int d = 0; d < 32; d++) s = fmaf(ah_s[a*32 + d], kf[d], s);
                int aidx = (a0 + a < AGENTS) ? (a0 + a) : (AGENTS - 1);
                s = s * scale + pbp[(size_t)aidx*NPIX + pix];
                float p = __expf(s);
                pv[a] = (a < cnt) ? p : 0.f;
                lp[a] += pv[a];
            }
            *(f32x4*)&p_s[pix*4] = pv;
        }
        // l reduction: wave shuffle then LDS
#pragma unroll
        for (int a = 0; a < 4; a++)
            for (int off = 32; off > 0; off >>= 1)
                lp[a] += __shfl_down(lp[a], off, 64);
        if ((tid & 63) == 0) {
            int wv = tid >> 6;
#pragma unroll
            for (int a = 0; a < 4; a++) lred[wv*4 + a] = lp[a];
        }
        __syncthreads();
        if (tid < 4) {
            float s = 0.f;
#pragma unroll
            for (int wv = 0; wv < 8; wv++) s += lred[wv*4 + tid];
            l_s[tid] = s;
        }
        // phase B: acc[a][d] = sum_pix p * v
        int d = tid & 31, g = tid >> 5;       // g: 0..15
        f32x4 a4 = {};
        for (int pix = g; pix < NPIX; pix += 16) {
            f32x4 p4 = *(const f32x4*)&p_s[pix*4];
            float vv = bf2f(vptr[(size_t)pix*HD + d]);
            a4 += p4 * vv;
        }
#pragma unroll
        for (int a = 0; a < 4; a++) red[(g*4 + a)*32 + d] = a4[a];
        __syncthreads();
        if (tid < 128) {
            int a = tid >> 5, dd = tid & 31;
            float s = 0.f;
#pragma unroll
            for (int g2 = 0; g2 < 16; g2++) s += red[(g2*4 + a)*32 + dd];
            if (a < cnt) agentv[((size_t)bh*AGENTS + a0 + a)*HD + dd] = s / l_s[a];
        }
        __syncthreads();
    }
}

// ---------------- stage 2: o[pix,:] = softmax_a(scale*q.ah + ab1) @ agent_v -> obuf bf16 ----------------
__global__ __launch_bounds__(256) void stage2(const u16* __restrict__ qb, const float* __restrict__ agent,
                                              const float* __restrict__ agentv, const float* __restrict__ ab1,
                                              u16* __restrict__ obuf) {
    __shared__ float ah_s[AGENTS*32];
    __shared__ float av_s[AGENTS*32];
    const int b = blockIdx.z, hh = blockIdx.y, chunk = blockIdx.x;
    const int bh = b*HEADS + hh;
    for (int i = threadIdx.x; i < AGENTS*32; i += 256) {
        ah_s[i] = agent[(size_t)bh*AGENTS*HD + i];
        av_s[i] = agentv[(size_t)bh*AGENTS*HD + i];
    }
    __syncthreads();
    int pix = chunk*256 + threadIdx.x;
    if (pix >= NPIX) return;
    const float scale = 0.1767766952966369f;
    float qf[32];
    unpack_row32(qb + ((size_t)bh*NPIX + pix)*HD, qf);
    float oacc[32];
#pragma unroll
    for (int d = 0; d < 32; d++) oacc[d] = 0.f;
    float l = 0.f;
    const float* abp = ab1 + (size_t)hh*AGENTS*NPIX + pix;
    for (int a = 0; a < AGENTS; a++) {
        float s = 0.f;
#pragma unroll
        for (int d = 0; d < 32; d++) s = fmaf(qf[d], ah_s[a*32 + d], s);
        s = s * scale + abp[(size_t)a*NPIX];
        float p = __expf(s);
        l += p;
#pragma unroll
        for (int d = 0; d < 32; d++) oacc[d] = fmaf(p, av_s[a*32 + d], oacc[d]);
    }
    float inv = 1.f / l;
    u16* op = obuf + ((size_t)b*NPIX + pix)*DIM + hh*HD;
#pragma unroll
    for (int d2 = 0; d2 < 16; d2++) {
        u32 lo = f2bf(oacc[2*d2] * inv);
        u32 hi = f2bf(oacc[2*d2 + 1] * inv);
        ((u32*)op)[d2] = lo | (hi << 16);
    }
}

// ---------------- depthwise 3x3 conv on V (fp32 weights), added into obuf (bf16) ----------------
__global__ __launch_bounds__(256) void dwconv_add(const u16* __restrict__ vb, const float* __restrict__ dwcw,
                                                  const float* __restrict__ dwcb, u16* __restrict__ obuf) {
    const int chunk = blockIdx.x;       // 0..97 (32 pixels each)
    const int hh = blockIdx.y, b = blockIdx.z;
    const int dd = threadIdx.x & 31, pg = threadIdx.x >> 5;
    const int ch = hh*HD + dd;
    float wgt[9];
#pragma unroll
    for (int i = 0; i < 9; i++) wgt[i] = dwcw[ch*9 + i];
    float bbias = dwcb[ch];
    const u16* vp = vb + (size_t)(b*HEADS + hh)*NPIX*HD + dd;
#pragma unroll
    for (int i = 0; i < 4; i++) {
        int pix = chunk*32 + i*8 + pg;
        int y = pix / 56, x0 = pix - y*56;
        float s = bbias;
#pragma unroll
        for (int dy = 0; dy < 3; dy++) {
            int yy = y + dy - 1;
            if (yy < 0 || yy > 55) continue;
#pragma unroll
            for (int dx = 0; dx < 3; dx++) {
                int xx = x0 + dx - 1;
                if (xx < 0 || xx > 55) continue;
                s = fmaf(wgt[dy*3 + dx], bf2f(vp[(size_t)(yy*56 + xx)*HD]), s);
            }
        }
        size_t oi = ((size_t)b*NPIX + pix)*DIM + ch;
        obuf[oi] = f2bf(bf2f(obuf[oi]) + s);
    }
}

// ---------------- launch ----------------
extern "C" void kernel_launch(void* const* d_in, const int* in_sizes, int n_in,
                              void* d_out, int out_size, void* d_ws, size_t ws_size,
                              hipStream_t stream) {
    const float* x     = (const float*)d_in[0];
    const float* qkvw  = (const float*)d_in[1];
    const float* qkvb  = (const float*)d_in[2];
    const float* projw = (const float*)d_in[3];
    const float* projb = (const float*)d_in[4];
    const float* anb   = (const float*)d_in[5];
    const float* nab   = (const float*)d_in[6];
    const float* dwcw  = (const float*)d_in[7];
    const float* dwcb  = (const float*)d_in[8];
    float* out = (float*)d_out;

    // d_ws layout (221.6 MiB total)
    char* w = (char*)d_ws;
    const size_t SZ_BNC = (size_t)BATCH*NPIX*DIM*2;          // 77,070,336 B (bf16)
    u16* qb     = (u16*)w;  w += SZ_BNC;
    u16* kb     = (u16*)w;  w += SZ_BNC;                     // reused as obuf after stage1
    u16* vb     = (u16*)w;  w += SZ_BNC;
    u16* qkvwT  = (u16*)w;  w += (size_t)1152*384*2;
    u16* projwT = (u16*)w;  w += (size_t)384*384*2;
    u16* obuf   = kb;

    // stage-only fp32 buffers live in d_out (49.3 MB; all dead before gemm_proj rewrites d_out)
    char* o = (char*)d_out;
    float* pb1    = (float*)o; o += (size_t)HEADS*AGENTS*NPIX*4;   //  7.38 MB
    float* ab1    = (float*)o; o += (size_t)HEADS*AGENTS*NPIX*4;   //  7.38 MB
    float* agent  = (float*)o; o += (size_t)BATCH*HEADS*AGENTS*HD*4;
    float* agentv = (float*)o; o += (size_t)BATCH*HEADS*AGENTS*HD*4;  // total 19.6 MB < 49.3 MB

    transpose_mat<<<dim3(18, 6),     256, 0, stream>>>(qkvw, qkvwT, 384, 1152);
    transpose_mat<<<dim3(6, 6),      256, 0, stream>>>(projw, projwT, 384, 384);
    upsample_bias<<<dim3(7203),      256, 0, stream>>>(anb, pb1);
    upsample_bias<<<dim3(7203),      256, 0, stream>>>(nab, ab1);
    gemm_qkv     <<<dim3(9, 25, 32), 256, 0, stream>>>(x, qkvwT, qkvb, qb, kb, vb);
    pool_q       <<<dim3(2352),      256, 0, stream>>>(qb, agent);
    stage1       <<<dim3(384),       512, 0, stream>>>(kb, vb, agent, pb1, agentv);
    stage2       <<<dim3(13, 12, 32),256, 0, stream>>>(qb, agent, agentv, ab1, obuf);
    dwconv_add   <<<dim3(98, 12, 32),256, 0, stream>>>(vb, dwcw, dwcb, obuf);
    gemm_proj    <<<dim3(3, 784),    256, 0, stream>>>(obuf, projwT, projb, x, out);
}